// Round 5
// baseline (893.304 us; speedup 1.0000x reference)
//
#include <hip/hip_runtime.h>
#include <hip/hip_bf16.h>

// ---------------- problem constants ----------------
#define T_TOKENS 8192
#define HD 1024
#define FF 4096
#define NEXP 8
#define NR_MAX 17408   // 16384 picks + 8 experts * 127 max pad, rounded to 128

typedef __attribute__((ext_vector_type(8))) short bf16x8;
typedef __attribute__((ext_vector_type(4))) float f32x4;
typedef unsigned short ushort8v __attribute__((ext_vector_type(8)));

static __device__ __forceinline__ float b2f(ushort u) {
    union { unsigned u; float f; } c; c.u = ((unsigned)u) << 16; return c.f;
}
static __device__ __forceinline__ ushort f2b(float f) {
    union { float f; unsigned u; } c; c.f = f;
    unsigned r = c.u + 0x7fffu + ((c.u >> 16) & 1u);   // RNE
    return (ushort)(r >> 16);
}

// ---------------- gate: logits, softmax, top-2, counts ----------------
__global__ __launch_bounds__(256) void gate_kernel(
    const float* __restrict__ x, const float* __restrict__ Wg, const float* __restrict__ bg,
    float* __restrict__ logits, int* __restrict__ counts,
    int* __restrict__ e0a, int* __restrict__ e1a,
    float* __restrict__ w0a, float* __restrict__ w1a)
{
    int t = blockIdx.x * 4 + (threadIdx.x >> 6);
    int l = threadIdx.x & 63;
    const float* xr = x + (size_t)t * HD;
    float acc[8] = {0,0,0,0,0,0,0,0};
    #pragma unroll
    for (int i = 0; i < 4; ++i) {
        int h0 = i * 256 + l * 4;
        float4 xv = *(const float4*)(xr + h0);
        #pragma unroll
        for (int j = 0; j < 4; ++j) {
            float xs = (&xv.x)[j];
            const float4* wr = (const float4*)(Wg + (size_t)(h0 + j) * NEXP);
            float4 wa = wr[0], wb = wr[1];
            acc[0] = fmaf(xs, wa.x, acc[0]);
            acc[1] = fmaf(xs, wa.y, acc[1]);
            acc[2] = fmaf(xs, wa.z, acc[2]);
            acc[3] = fmaf(xs, wa.w, acc[3]);
            acc[4] = fmaf(xs, wb.x, acc[4]);
            acc[5] = fmaf(xs, wb.y, acc[5]);
            acc[6] = fmaf(xs, wb.z, acc[6]);
            acc[7] = fmaf(xs, wb.w, acc[7]);
        }
    }
    #pragma unroll
    for (int off = 32; off > 0; off >>= 1) {
        #pragma unroll
        for (int e = 0; e < 8; ++e) acc[e] += __shfl_down(acc[e], off, 64);
    }
    if (l == 0) {
        float lg[8];
        #pragma unroll
        for (int e = 0; e < 8; ++e) {
            lg[e] = acc[e] + bg[e];
            logits[(size_t)t * NEXP + e] = lg[e];
        }
        float m = lg[0];
        #pragma unroll
        for (int e = 1; e < 8; ++e) m = fmaxf(m, lg[e]);
        float p[8], s = 0.f;
        #pragma unroll
        for (int e = 0; e < 8; ++e) { p[e] = expf(lg[e] - m); s += p[e]; }
        float inv = 1.f / s;
        #pragma unroll
        for (int e = 0; e < 8; ++e) p[e] *= inv;
        int i0 = 0;
        #pragma unroll
        for (int e = 1; e < 8; ++e) if (p[e] > p[i0]) i0 = e;
        int i1 = (i0 == 0) ? 1 : 0;
        #pragma unroll
        for (int e = 0; e < 8; ++e) if (e != i0 && p[e] > p[i1]) i1 = e;
        float ed = expf(p[i1] - p[i0]);          // <= 1
        float w0 = 1.f / (1.f + ed);
        float w1 = ed / (1.f + ed);
        e0a[t] = i0; e1a[t] = i1; w0a[t] = w0; w1a[t] = w1;
        atomicAdd(&counts[i0], 1);
        atomicAdd(&counts[i1], 1);
    }
}

// ---------------- offsets: pad each expert segment to 128 rows ----------------
__global__ void offsets_kernel(const int* __restrict__ counts, int* __restrict__ off) {
    if (threadIdx.x == 0) {
        int o = 0;
        for (int e = 0; e < 8; ++e) { off[e] = o; o += (counts[e] + 127) & ~127; }
        off[8] = o;
    }
}

// ---------------- assign rows ----------------
__global__ __launch_bounds__(256) void assign_kernel(
    const int* __restrict__ e0a, const int* __restrict__ e1a,
    const int* __restrict__ off, int* __restrict__ fill,
    int* __restrict__ row0, int* __restrict__ row1, int* __restrict__ row_token)
{
    int t = blockIdx.x * 256 + threadIdx.x;
    if (t >= T_TOKENS) return;
    int e0 = e0a[t];
    int r0 = off[e0] + atomicAdd(&fill[e0], 1);
    row0[t] = r0; row_token[r0] = t;
    int e1 = e1a[t];
    int r1 = off[e1] + atomicAdd(&fill[e1], 1);
    row1[t] = r1; row_token[r1] = t;
}

// ---------------- gather x rows -> bf16 X_perm (zeros in padding rows) ----------------
__global__ __launch_bounds__(256) void gather_kernel(
    const float* __restrict__ x, const int* __restrict__ row_token, ushort* __restrict__ Xp)
{
    int r = blockIdx.x;
    int tok = row_token[r];
    int c = threadIdx.x * 4;
    ushort4 o;
    if (tok >= 0 && tok < T_TOKENS) {
        float4 v = *(const float4*)(x + (size_t)tok * HD + c);
        o.x = f2b(v.x); o.y = f2b(v.y); o.z = f2b(v.z); o.w = f2b(v.w);
    } else {
        o.x = 0; o.y = 0; o.z = 0; o.w = 0;
    }
    *(ushort4*)(Xp + (size_t)r * HD + c) = o;
}

// ---------------- fp32 [R][C] -> bf16 [C][R] transpose+convert (per expert in z) ----------------
__global__ __launch_bounds__(256) void transpose_cvt_kernel(
    const float* __restrict__ in, ushort* __restrict__ out, int R, int C)
{
    __shared__ ushort tile[64][65];
    size_t esz = (size_t)R * C;
    const float* ein = in + (size_t)blockIdx.z * esz;
    ushort* eout = out + (size_t)blockIdx.z * esz;
    int c0 = blockIdx.x * 64, r0 = blockIdx.y * 64;
    int tr = threadIdx.x >> 4;            // 0..15
    int tc = (threadIdx.x & 15) * 4;      // 0..60
    #pragma unroll
    for (int i = 0; i < 4; ++i) {
        int r = tr + i * 16;
        float4 v = *(const float4*)(ein + (size_t)(r0 + r) * C + c0 + tc);
        tile[r][tc + 0] = f2b(v.x);
        tile[r][tc + 1] = f2b(v.y);
        tile[r][tc + 2] = f2b(v.z);
        tile[r][tc + 3] = f2b(v.w);
    }
    __syncthreads();
    int twc = threadIdx.x >> 3;           // 0..31 : output row (input col) within tile
    int twr = (threadIdx.x & 7) * 8;      // 0..56 : output col (input row) base
    #pragma unroll
    for (int i = 0; i < 2; ++i) {
        int cc = twc + i * 32;
        ushort8v v;
        #pragma unroll
        for (int j = 0; j < 8; ++j) v[j] = tile[twr + j][cc];
        *(ushort8v*)(eout + (size_t)(c0 + cc) * R + r0 + twr) = v;   // 16B store
    }
}

// ---------------- MFMA GEMM: 128x256 tile, 8 waves, m97-proven inner loop ----------------
// C[rows x NTOT] = A[rows x K] * B^T[NTOT x K] + bias. BK=32, waves 2x4 of 64x64.
// global_load_lds width 16 with pre-swizzled source; conflict-free ds_read swizzle.
// NTSTORE: nontemporal output stores (protect L3 residency of weights).
template<int K, int NTOT, bool RELU, bool NTSTORE>
__global__ __launch_bounds__(512) void gemm_kernel(
    const ushort* __restrict__ A, const ushort* __restrict__ Bt,
    const float* __restrict__ bias, ushort* __restrict__ Out,
    const int* __restrict__ off)
{
    constexpr int BN = 256;
    constexpr int NT = NTOT / BN;
    __shared__ __align__(16) ushort ldsA[2][128 * 32];
    __shared__ __align__(16) ushort ldsB[2][BN * 32];

    // bijective XCD swizzle (gridDim.x % 8 == 0); n-fastest within each chunk
    int nwg = gridDim.x;
    int bid = blockIdx.x;
    int wgid = (bid & 7) * (nwg >> 3) + (bid >> 3);
    int ntile = wgid % NT;
    int mtile = wgid / NT;
    int r0 = mtile * 128;
    int total = off[8];
    if (r0 >= total) return;
    int e = 0;
    #pragma unroll
    for (int q = 0; q < 7; ++q) if (r0 >= off[q + 1]) e = q + 1;

    int tid = threadIdx.x;
    int wid = tid >> 6, lane = tid & 63;
    int wr = wid >> 2, wc = wid & 3;       // 2 x 4 waves of 64x64
    int lr = lane & 15, lk = lane >> 4;

    const ushort* Ab = A + (size_t)r0 * K;
    const ushort* Bb = Bt + ((size_t)e * NTOT + (size_t)ntile * BN) * K;

    int srow = tid >> 2;                              // 0..127
    int schunk = (tid & 3) ^ ((tid >> 3) & 3);        // proven conflict-free pre-swizzle

    auto stageA = [&](int kt, int buf) {
        const ushort* g = Ab + (size_t)kt * 32 + (size_t)srow * K + schunk * 8;
        __builtin_amdgcn_global_load_lds(
            (const __attribute__((address_space(1))) void*)g,
            (__attribute__((address_space(3))) void*)&ldsA[buf][tid * 8], 16, 0, 0);
    };
    auto stageB = [&](int kt, int buf) {
        #pragma unroll
        for (int i = 0; i < 2; ++i) {
            const ushort* g = Bb + (size_t)kt * 32 + (size_t)(i * 128 + srow) * K + schunk * 8;
            __builtin_amdgcn_global_load_lds(
                (const __attribute__((address_space(1))) void*)g,
                (__attribute__((address_space(3))) void*)&ldsB[buf][i * 4096 + tid * 8], 16, 0, 0);
        }
    };

    stageA(0, 0); stageB(0, 0);

    f32x4 acc[4][4];
    #pragma unroll
    for (int mi = 0; mi < 4; ++mi)
        #pragma unroll
        for (int ni = 0; ni < 4; ++ni) acc[mi][ni] = (f32x4){0.f, 0.f, 0.f, 0.f};

    __syncthreads();

    constexpr int KT = K / 32;
    int cur = 0;
    int slot = lk ^ ((lr >> 1) & 3);                  // conflict-free read slot
    for (int kt = 0; kt < KT; ++kt) {
        if (kt + 1 < KT) { stageA(kt + 1, cur ^ 1); stageB(kt + 1, cur ^ 1); }
        const ushort* As = &ldsA[cur][0];
        const ushort* Bs = &ldsB[cur][0];
        bf16x8 a[4], b[4];
        #pragma unroll
        for (int mi = 0; mi < 4; ++mi)
            a[mi] = *(const bf16x8*)(As + (wr * 64 + mi * 16 + lr) * 32 + slot * 8);
        #pragma unroll
        for (int ni = 0; ni < 4; ++ni)
            b[ni] = *(const bf16x8*)(Bs + (wc * 64 + ni * 16 + lr) * 32 + slot * 8);
        #pragma unroll
        for (int mi = 0; mi < 4; ++mi)
            #pragma unroll
            for (int ni = 0; ni < 4; ++ni)
                acc[mi][ni] = __builtin_amdgcn_mfma_f32_16x16x32_bf16(
                    a[mi], b[ni], acc[mi][ni], 0, 0, 0);
        __syncthreads();
        cur ^= 1;
    }

    // epilogue: bias (+ReLU) -> bf16 store. C/D map: col = lane&15, row = (lane>>4)*4 + j
    int c0 = ntile * BN + wc * 64;
    int rbase = r0 + wr * 64;
    #pragma unroll
    for (int ni = 0; ni < 4; ++ni) {
        int n = c0 + ni * 16 + lr;
        float bv = bias[(size_t)e * NTOT + n];
        #pragma unroll
        for (int mi = 0; mi < 4; ++mi) {
            int m = rbase + mi * 16 + lk * 4;
            #pragma unroll
            for (int j = 0; j < 4; ++j) {
                float v = acc[mi][ni][j] + bv;
                if (RELU) v = fmaxf(v, 0.f);
                ushort* p = &Out[(size_t)(m + j) * NTOT + n];
                if (NTSTORE) __builtin_nontemporal_store(f2b(v), p);
                else *p = f2b(v);
            }
        }
    }
}

// ---------------- combine: out[t] = w0*Y[r0] + w1*Y[r1] ----------------
__global__ __launch_bounds__(256) void combine_kernel(
    const ushort* __restrict__ Y, const int* __restrict__ row0, const int* __restrict__ row1,
    const float* __restrict__ w0a, const float* __restrict__ w1a, float* __restrict__ out)
{
    int t = blockIdx.x;
    int c = threadIdx.x * 4;
    int r0 = row0[t], r1 = row1[t];
    float w0 = w0a[t], w1 = w1a[t];
    ushort4 ya = *(const ushort4*)(Y + (size_t)r0 * HD + c);
    ushort4 yb = *(const ushort4*)(Y + (size_t)r1 * HD + c);
    float4 o;
    o.x = w0 * b2f(ya.x) + w1 * b2f(yb.x);
    o.y = w0 * b2f(ya.y) + w1 * b2f(yb.y);
    o.z = w0 * b2f(ya.z) + w1 * b2f(yb.z);
    o.w = w0 * b2f(ya.w) + w1 * b2f(yb.w);
    *(float4*)(out + (size_t)t * HD + c) = o;
}

// ---------------- workspace layout ----------------
#define WSA(x) (((x) + 255) & ~(size_t)255)
static constexpr size_t OFF_COUNTS = 0;
static constexpr size_t OFF_FILL   = 64;
static constexpr size_t OFF_OFF    = 128;
static constexpr size_t OFF_E0     = 256;
static constexpr size_t OFF_E1     = OFF_E0 + (size_t)T_TOKENS * 4;
static constexpr size_t OFF_W0     = OFF_E1 + (size_t)T_TOKENS * 4;
static constexpr size_t OFF_W1A    = OFF_W0 + (size_t)T_TOKENS * 4;
static constexpr size_t OFF_R0     = OFF_W1A + (size_t)T_TOKENS * 4;
static constexpr size_t OFF_R1     = OFF_R0 + (size_t)T_TOKENS * 4;
static constexpr size_t OFF_RT     = OFF_R1 + (size_t)T_TOKENS * 4;
static constexpr size_t OFF_XP     = WSA(OFF_RT + (size_t)NR_MAX * 4);
static constexpr size_t OFF_W1T    = OFF_XP  + (size_t)NR_MAX * HD * 2;
static constexpr size_t OFF_W2T    = OFF_W1T + (size_t)NEXP * FF * HD * 2;
static constexpr size_t OFF_H1     = OFF_W2T + (size_t)NEXP * HD * FF * 2;
static constexpr size_t OFF_Y      = OFF_H1  + (size_t)NR_MAX * FF * 2;
static constexpr size_t WS_NEEDED  = OFF_Y   + (size_t)NR_MAX * HD * 2;

extern "C" void kernel_launch(void* const* d_in, const int* in_sizes, int n_in,
                              void* d_out, int out_size, void* d_ws, size_t ws_size,
                              hipStream_t stream) {
    (void)in_sizes; (void)n_in; (void)out_size;
    const float* x  = (const float*)d_in[0];
    const float* Wg = (const float*)d_in[1];
    const float* bg = (const float*)d_in[2];
    const float* W1 = (const float*)d_in[3];
    const float* b1 = (const float*)d_in[4];
    const float* W2 = (const float*)d_in[5];
    const float* b2 = (const float*)d_in[6];
    float* out    = (float*)d_out;
    float* logits = out + (size_t)T_TOKENS * HD;

    if (ws_size < WS_NEEDED) return;  // need ~349 MB scratch

    char* ws = (char*)d_ws;
    int*    counts = (int*)(ws + OFF_COUNTS);
    int*    fill   = (int*)(ws + OFF_FILL);
    int*    offp   = (int*)(ws + OFF_OFF);
    int*    e0a    = (int*)(ws + OFF_E0);
    int*    e1a    = (int*)(ws + OFF_E1);
    float*  w0a    = (float*)(ws + OFF_W0);
    float*  w1a    = (float*)(ws + OFF_W1A);
    int*    row0   = (int*)(ws + OFF_R0);
    int*    row1   = (int*)(ws + OFF_R1);
    int*    rowtok = (int*)(ws + OFF_RT);
    ushort* Xp     = (ushort*)(ws + OFF_XP);
    ushort* W1T    = (ushort*)(ws + OFF_W1T);
    ushort* W2T    = (ushort*)(ws + OFF_W2T);
    ushort* H1     = (ushort*)(ws + OFF_H1);
    ushort* Y      = (ushort*)(ws + OFF_Y);

    hipMemsetAsync(ws, 0, 256, stream);                         // counts/fill/off
    hipMemsetAsync(rowtok, 0xFF, (size_t)NR_MAX * 4, stream);   // row_token = -1

    gate_kernel<<<T_TOKENS / 4, 256, 0, stream>>>(x, Wg, bg, logits, counts, e0a, e1a, w0a, w1a);
    offsets_kernel<<<1, 64, 0, stream>>>(counts, offp);
    assign_kernel<<<T_TOKENS / 256, 256, 0, stream>>>(e0a, e1a, offp, fill, row0, row1, rowtok);
    gather_kernel<<<NR_MAX, 256, 0, stream>>>(x, rowtok, Xp);
    transpose_cvt_kernel<<<dim3(FF / 64, HD / 64, NEXP), 256, 0, stream>>>(W1, W1T, HD, FF);
    transpose_cvt_kernel<<<dim3(HD / 64, FF / 64, NEXP), 256, 0, stream>>>(W2, W2T, FF, HD);
    gemm_kernel<HD, FF, true, true>
        <<<(FF / 256) * (NR_MAX / 128), 512, 0, stream>>>(Xp, W1T, b1, H1, offp);
    gemm_kernel<FF, HD, false, false>
        <<<(HD / 256) * (NR_MAX / 128), 512, 0, stream>>>(H1, W2T, b2, Y, offp);
    combine_kernel<<<T_TOKENS, 256, 0, stream>>>(Y, row0, row1, w0a, w1a, out);
}

// Round 6
// 820.435 us; speedup vs baseline: 1.0888x; 1.0888x over previous
//
#include <hip/hip_runtime.h>
#include <hip/hip_bf16.h>

// ---------------- problem constants ----------------
#define T_TOKENS 8192
#define HD 1024
#define FF 4096
#define NEXP 8
#define NR_MAX 17408   // 16384 picks + 8 experts * 127 max pad, rounded to 128

typedef __attribute__((ext_vector_type(8))) short bf16x8;
typedef __attribute__((ext_vector_type(4))) float f32x4;
typedef unsigned short ushort8v __attribute__((ext_vector_type(8)));

static __device__ __forceinline__ float b2f(ushort u) {
    union { unsigned u; float f; } c; c.u = ((unsigned)u) << 16; return c.f;
}
static __device__ __forceinline__ ushort f2b(float f) {
    union { float f; unsigned u; } c; c.f = f;
    unsigned r = c.u + 0x7fffu + ((c.u >> 16) & 1u);   // RNE
    return (ushort)(r >> 16);
}

// ---------------- gate: logits, softmax, top-2, counts ----------------
__global__ __launch_bounds__(256) void gate_kernel(
    const float* __restrict__ x, const float* __restrict__ Wg, const float* __restrict__ bg,
    float* __restrict__ logits, int* __restrict__ counts,
    int* __restrict__ e0a, int* __restrict__ e1a,
    float* __restrict__ w0a, float* __restrict__ w1a)
{
    int t = blockIdx.x * 4 + (threadIdx.x >> 6);
    int l = threadIdx.x & 63;
    const float* xr = x + (size_t)t * HD;
    float acc[8] = {0,0,0,0,0,0,0,0};
    #pragma unroll
    for (int i = 0; i < 4; ++i) {
        int h0 = i * 256 + l * 4;
        float4 xv = *(const float4*)(xr + h0);
        #pragma unroll
        for (int j = 0; j < 4; ++j) {
            float xs = (&xv.x)[j];
            const float4* wr = (const float4*)(Wg + (size_t)(h0 + j) * NEXP);
            float4 wa = wr[0], wb = wr[1];
            acc[0] = fmaf(xs, wa.x, acc[0]);
            acc[1] = fmaf(xs, wa.y, acc[1]);
            acc[2] = fmaf(xs, wa.z, acc[2]);
            acc[3] = fmaf(xs, wa.w, acc[3]);
            acc[4] = fmaf(xs, wb.x, acc[4]);
            acc[5] = fmaf(xs, wb.y, acc[5]);
            acc[6] = fmaf(xs, wb.z, acc[6]);
            acc[7] = fmaf(xs, wb.w, acc[7]);
        }
    }
    #pragma unroll
    for (int off = 32; off > 0; off >>= 1) {
        #pragma unroll
        for (int e = 0; e < 8; ++e) acc[e] += __shfl_down(acc[e], off, 64);
    }
    if (l == 0) {
        float lg[8];
        #pragma unroll
        for (int e = 0; e < 8; ++e) {
            lg[e] = acc[e] + bg[e];
            logits[(size_t)t * NEXP + e] = lg[e];
        }
        float m = lg[0];
        #pragma unroll
        for (int e = 1; e < 8; ++e) m = fmaxf(m, lg[e]);
        float p[8], s = 0.f;
        #pragma unroll
        for (int e = 0; e < 8; ++e) { p[e] = expf(lg[e] - m); s += p[e]; }
        float inv = 1.f / s;
        #pragma unroll
        for (int e = 0; e < 8; ++e) p[e] *= inv;
        int i0 = 0;
        #pragma unroll
        for (int e = 1; e < 8; ++e) if (p[e] > p[i0]) i0 = e;
        int i1 = (i0 == 0) ? 1 : 0;
        #pragma unroll
        for (int e = 0; e < 8; ++e) if (e != i0 && p[e] > p[i1]) i1 = e;
        float ed = expf(p[i1] - p[i0]);          // <= 1
        float w0 = 1.f / (1.f + ed);
        float w1 = ed / (1.f + ed);
        e0a[t] = i0; e1a[t] = i1; w0a[t] = w0; w1a[t] = w1;
        atomicAdd(&counts[i0], 1);
        atomicAdd(&counts[i1], 1);
    }
}

// ---------------- offsets: pad each expert segment to 128 rows ----------------
__global__ void offsets_kernel(const int* __restrict__ counts, int* __restrict__ off) {
    if (threadIdx.x == 0) {
        int o = 0;
        for (int e = 0; e < 8; ++e) { off[e] = o; o += (counts[e] + 127) & ~127; }
        off[8] = o;
    }
}

// ---------------- assign rows ----------------
__global__ __launch_bounds__(256) void assign_kernel(
    const int* __restrict__ e0a, const int* __restrict__ e1a,
    const int* __restrict__ off, int* __restrict__ fill,
    int* __restrict__ row0, int* __restrict__ row1, int* __restrict__ row_token)
{
    int t = blockIdx.x * 256 + threadIdx.x;
    if (t >= T_TOKENS) return;
    int e0 = e0a[t];
    int r0 = off[e0] + atomicAdd(&fill[e0], 1);
    row0[t] = r0; row_token[r0] = t;
    int e1 = e1a[t];
    int r1 = off[e1] + atomicAdd(&fill[e1], 1);
    row1[t] = r1; row_token[r1] = t;
}

// ---------------- gather x rows -> bf16 X_perm (zeros in padding rows) ----------------
__global__ __launch_bounds__(256) void gather_kernel(
    const float* __restrict__ x, const int* __restrict__ row_token, ushort* __restrict__ Xp)
{
    int r = blockIdx.x;
    int tok = row_token[r];
    int c = threadIdx.x * 4;
    ushort4 o;
    if (tok >= 0 && tok < T_TOKENS) {
        float4 v = *(const float4*)(x + (size_t)tok * HD + c);
        o.x = f2b(v.x); o.y = f2b(v.y); o.z = f2b(v.z); o.w = f2b(v.w);
    } else {
        o.x = 0; o.y = 0; o.z = 0; o.w = 0;
    }
    *(ushort4*)(Xp + (size_t)r * HD + c) = o;
}

// ---------------- fp32 [R][C] -> bf16 [C][R] transpose+convert (per expert in z) ----------------
__global__ __launch_bounds__(256) void transpose_cvt_kernel(
    const float* __restrict__ in, ushort* __restrict__ out, int R, int C)
{
    __shared__ ushort tile[64][65];
    size_t esz = (size_t)R * C;
    const float* ein = in + (size_t)blockIdx.z * esz;
    ushort* eout = out + (size_t)blockIdx.z * esz;
    int c0 = blockIdx.x * 64, r0 = blockIdx.y * 64;
    int tr = threadIdx.x >> 4;            // 0..15
    int tc = (threadIdx.x & 15) * 4;      // 0..60
    #pragma unroll
    for (int i = 0; i < 4; ++i) {
        int r = tr + i * 16;
        float4 v = *(const float4*)(ein + (size_t)(r0 + r) * C + c0 + tc);
        tile[r][tc + 0] = f2b(v.x);
        tile[r][tc + 1] = f2b(v.y);
        tile[r][tc + 2] = f2b(v.z);
        tile[r][tc + 3] = f2b(v.w);
    }
    __syncthreads();
    int twc = threadIdx.x >> 3;           // 0..31 : output row (input col) within tile
    int twr = (threadIdx.x & 7) * 8;      // 0..56 : output col (input row) base
    #pragma unroll
    for (int i = 0; i < 2; ++i) {
        int cc = twc + i * 32;
        ushort8v v;
        #pragma unroll
        for (int j = 0; j < 8; ++j) v[j] = tile[twr + j][cc];
        *(ushort8v*)(eout + (size_t)(c0 + cc) * R + r0 + twr) = v;   // 16B store
    }
}

// ---------------- MFMA GEMM (round-4-proven structure + XCD swizzle + NT store) ----------------
// C[rows x NTOT] = A[rows x K] * B^T[NTOT x K] + bias, 128x128 tile, BK=32,
// 4 waves (2x2 of 64x64), mfma_f32_16x16x32_bf16, compiler-scheduled 2-barrier
// dbuf loop, global_load_lds width 16 with pre-swizzled source (0 bank conflicts).
// NTSTORE=true: nontemporal output stores (keep weight panels L3-resident).
template<int K, int NTOT, bool RELU, bool NTSTORE>
__global__ __launch_bounds__(256) void gemm_kernel(
    const ushort* __restrict__ A, const ushort* __restrict__ Bt,
    const float* __restrict__ bias, ushort* __restrict__ Out,
    const int* __restrict__ off)
{
    constexpr int NT = NTOT / 128;
    __shared__ __align__(16) ushort lds[2][2][128 * 32];

    // bijective XCD swizzle (gridDim.x % 8 == 0); n-fastest within each chunk
    int nwg = gridDim.x;
    int bid = blockIdx.x;
    int wgid = (bid & 7) * (nwg >> 3) + (bid >> 3);
    int ntile = wgid % NT;
    int mtile = wgid / NT;
    int r0 = mtile * 128;
    int total = off[8];
    if (r0 >= total) return;
    int e = 0;
    #pragma unroll
    for (int q = 0; q < 7; ++q) if (r0 >= off[q + 1]) e = q + 1;

    int tid = threadIdx.x;
    int w = tid >> 6, lane = tid & 63;
    int wr = w >> 1, wc = w & 1;
    int lr = lane & 15, lk = lane >> 4;

    const ushort* Ab = A + (size_t)r0 * K;
    const ushort* Bb = Bt + ((size_t)e * NTOT + (size_t)ntile * 128) * K;

    auto stage = [&](const ushort* gbase, ushort* ldsbase) {
        #pragma unroll
        for (int issue = 0; issue < 2; ++issue) {
            int row = issue * 64 + w * 16 + (lane >> 2);
            int chunk = (lane & 3) ^ ((lane >> 3) & 3);   // pre-swizzle source
            const ushort* g = gbase + (size_t)row * K + chunk * 8;
            ushort* lp = ldsbase + (issue * 64 + w * 16) * 32;
            __builtin_amdgcn_global_load_lds(
                (const __attribute__((address_space(1))) void*)g,
                (__attribute__((address_space(3))) void*)lp, 16, 0, 0);
        }
    };

    stage(Ab, &lds[0][0][0]);
    stage(Bb, &lds[0][1][0]);

    f32x4 acc[4][4];
    #pragma unroll
    for (int mi = 0; mi < 4; ++mi)
        #pragma unroll
        for (int ni = 0; ni < 4; ++ni) acc[mi][ni] = (f32x4){0.f, 0.f, 0.f, 0.f};

    __syncthreads();

    constexpr int KT = K / 32;
    int cur = 0;
    int slot = lk ^ ((lr >> 1) & 3);                      // swizzled read slot
    for (int kt = 0; kt < KT; ++kt) {
        if (kt + 1 < KT) {
            stage(Ab + (kt + 1) * 32, &lds[cur ^ 1][0][0]);
            stage(Bb + (kt + 1) * 32, &lds[cur ^ 1][1][0]);
        }
        const ushort* As = &lds[cur][0][0];
        const ushort* Bs = &lds[cur][1][0];
        bf16x8 a[4], b[4];
        #pragma unroll
        for (int mi = 0; mi < 4; ++mi)
            a[mi] = *(const bf16x8*)(As + (wr * 64 + mi * 16 + lr) * 32 + slot * 8);
        #pragma unroll
        for (int ni = 0; ni < 4; ++ni)
            b[ni] = *(const bf16x8*)(Bs + (wc * 64 + ni * 16 + lr) * 32 + slot * 8);
        #pragma unroll
        for (int mi = 0; mi < 4; ++mi)
            #pragma unroll
            for (int ni = 0; ni < 4; ++ni)
                acc[mi][ni] = __builtin_amdgcn_mfma_f32_16x16x32_bf16(
                    a[mi], b[ni], acc[mi][ni], 0, 0, 0);
        __syncthreads();
        cur ^= 1;
    }

    // epilogue: bias (+ReLU) -> bf16 store. C/D map: col = lane&15, row = (lane>>4)*4 + j
    int c0 = ntile * 128 + wc * 64;
    int rbase = r0 + wr * 64;
    #pragma unroll
    for (int ni = 0; ni < 4; ++ni) {
        int n = c0 + ni * 16 + lr;
        float bv = bias[(size_t)e * NTOT + n];
        #pragma unroll
        for (int mi = 0; mi < 4; ++mi) {
            int m = rbase + mi * 16 + lk * 4;
            #pragma unroll
            for (int j = 0; j < 4; ++j) {
                float v = acc[mi][ni][j] + bv;
                if (RELU) v = fmaxf(v, 0.f);
                ushort* p = &Out[(size_t)(m + j) * NTOT + n];
                if (NTSTORE) __builtin_nontemporal_store(f2b(v), p);
                else *p = f2b(v);
            }
        }
    }
}

// ---------------- combine: out[t] = w0*Y[r0] + w1*Y[r1] ----------------
__global__ __launch_bounds__(256) void combine_kernel(
    const ushort* __restrict__ Y, const int* __restrict__ row0, const int* __restrict__ row1,
    const float* __restrict__ w0a, const float* __restrict__ w1a, float* __restrict__ out)
{
    int t = blockIdx.x;
    int c = threadIdx.x * 4;
    int r0 = row0[t], r1 = row1[t];
    float w0 = w0a[t], w1 = w1a[t];
    ushort4 ya = *(const ushort4*)(Y + (size_t)r0 * HD + c);
    ushort4 yb = *(const ushort4*)(Y + (size_t)r1 * HD + c);
    float4 o;
    o.x = w0 * b2f(ya.x) + w1 * b2f(yb.x);
    o.y = w0 * b2f(ya.y) + w1 * b2f(yb.y);
    o.z = w0 * b2f(ya.z) + w1 * b2f(yb.z);
    o.w = w0 * b2f(ya.w) + w1 * b2f(yb.w);
    *(float4*)(out + (size_t)t * HD + c) = o;
}

// ---------------- workspace layout ----------------
#define WSA(x) (((x) + 255) & ~(size_t)255)
static constexpr size_t OFF_COUNTS = 0;
static constexpr size_t OFF_FILL   = 64;
static constexpr size_t OFF_OFF    = 128;
static constexpr size_t OFF_E0     = 256;
static constexpr size_t OFF_E1     = OFF_E0 + (size_t)T_TOKENS * 4;
static constexpr size_t OFF_W0     = OFF_E1 + (size_t)T_TOKENS * 4;
static constexpr size_t OFF_W1A    = OFF_W0 + (size_t)T_TOKENS * 4;
static constexpr size_t OFF_R0     = OFF_W1A + (size_t)T_TOKENS * 4;
static constexpr size_t OFF_R1     = OFF_R0 + (size_t)T_TOKENS * 4;
static constexpr size_t OFF_RT     = OFF_R1 + (size_t)T_TOKENS * 4;
static constexpr size_t OFF_XP     = WSA(OFF_RT + (size_t)NR_MAX * 4);
static constexpr size_t OFF_W1T    = OFF_XP  + (size_t)NR_MAX * HD * 2;
static constexpr size_t OFF_W2T    = OFF_W1T + (size_t)NEXP * FF * HD * 2;
static constexpr size_t OFF_H1     = OFF_W2T + (size_t)NEXP * HD * FF * 2;
static constexpr size_t OFF_Y      = OFF_H1  + (size_t)NR_MAX * FF * 2;
static constexpr size_t WS_NEEDED  = OFF_Y   + (size_t)NR_MAX * HD * 2;

extern "C" void kernel_launch(void* const* d_in, const int* in_sizes, int n_in,
                              void* d_out, int out_size, void* d_ws, size_t ws_size,
                              hipStream_t stream) {
    (void)in_sizes; (void)n_in; (void)out_size;
    const float* x  = (const float*)d_in[0];
    const float* Wg = (const float*)d_in[1];
    const float* bg = (const float*)d_in[2];
    const float* W1 = (const float*)d_in[3];
    const float* b1 = (const float*)d_in[4];
    const float* W2 = (const float*)d_in[5];
    const float* b2 = (const float*)d_in[6];
    float* out    = (float*)d_out;
    float* logits = out + (size_t)T_TOKENS * HD;

    if (ws_size < WS_NEEDED) return;  // need ~349 MB scratch

    char* ws = (char*)d_ws;
    int*    counts = (int*)(ws + OFF_COUNTS);
    int*    fill   = (int*)(ws + OFF_FILL);
    int*    offp   = (int*)(ws + OFF_OFF);
    int*    e0a    = (int*)(ws + OFF_E0);
    int*    e1a    = (int*)(ws + OFF_E1);
    float*  w0a    = (float*)(ws + OFF_W0);
    float*  w1a    = (float*)(ws + OFF_W1A);
    int*    row0   = (int*)(ws + OFF_R0);
    int*    row1   = (int*)(ws + OFF_R1);
    int*    rowtok = (int*)(ws + OFF_RT);
    ushort* Xp     = (ushort*)(ws + OFF_XP);
    ushort* W1T    = (ushort*)(ws + OFF_W1T);
    ushort* W2T    = (ushort*)(ws + OFF_W2T);
    ushort* H1     = (ushort*)(ws + OFF_H1);
    ushort* Y      = (ushort*)(ws + OFF_Y);

    hipMemsetAsync(ws, 0, 256, stream);                         // counts/fill/off
    hipMemsetAsync(rowtok, 0xFF, (size_t)NR_MAX * 4, stream);   // row_token = -1

    gate_kernel<<<T_TOKENS / 4, 256, 0, stream>>>(x, Wg, bg, logits, counts, e0a, e1a, w0a, w1a);
    offsets_kernel<<<1, 64, 0, stream>>>(counts, offp);
    assign_kernel<<<T_TOKENS / 256, 256, 0, stream>>>(e0a, e1a, offp, fill, row0, row1, rowtok);
    gather_kernel<<<NR_MAX, 256, 0, stream>>>(x, rowtok, Xp);
    transpose_cvt_kernel<<<dim3(FF / 64, HD / 64, NEXP), 256, 0, stream>>>(W1, W1T, HD, FF);
    transpose_cvt_kernel<<<dim3(HD / 64, FF / 64, NEXP), 256, 0, stream>>>(W2, W2T, FF, HD);
    gemm_kernel<HD, FF, true, true>
        <<<(FF / 128) * (NR_MAX / 128), 256, 0, stream>>>(Xp, W1T, b1, H1, offp);
    gemm_kernel<FF, HD, false, false>
        <<<(HD / 128) * (NR_MAX / 128), 256, 0, stream>>>(H1, W2T, b2, Y, offp);
    combine_kernel<<<T_TOKENS, 256, 0, stream>>>(Y, row0, row1, w0a, w1a, out);
}

// Round 7
// 794.783 us; speedup vs baseline: 1.1240x; 1.0323x over previous
//
#include <hip/hip_runtime.h>
#include <hip/hip_bf16.h>

// ---------------- problem constants ----------------
#define T_TOKENS 8192
#define HD 1024
#define FF 4096
#define NEXP 8
#define NR_MAX 17408   // 16384 picks + 8 experts * 127 max pad, rounded to 128

typedef __attribute__((ext_vector_type(8))) short bf16x8;
typedef __attribute__((ext_vector_type(4))) float f32x4;
typedef unsigned short ushort8v __attribute__((ext_vector_type(8)));

static __device__ __forceinline__ float b2f(ushort u) {
    union { unsigned u; float f; } c; c.u = ((unsigned)u) << 16; return c.f;
}
static __device__ __forceinline__ ushort f2b(float f) {
    union { float f; unsigned u; } c; c.f = f;
    unsigned r = c.u + 0x7fffu + ((c.u >> 16) & 1u);   // RNE
    return (ushort)(r >> 16);
}

// ---------------- gate: logits, softmax, top-2, counts ----------------
__global__ __launch_bounds__(256) void gate_kernel(
    const float* __restrict__ x, const float* __restrict__ Wg, const float* __restrict__ bg,
    float* __restrict__ logits, int* __restrict__ counts,
    int* __restrict__ e0a, int* __restrict__ e1a,
    float* __restrict__ w0a, float* __restrict__ w1a)
{
    int t = blockIdx.x * 4 + (threadIdx.x >> 6);
    int l = threadIdx.x & 63;
    const float* xr = x + (size_t)t * HD;
    float acc[8] = {0,0,0,0,0,0,0,0};
    #pragma unroll
    for (int i = 0; i < 4; ++i) {
        int h0 = i * 256 + l * 4;
        float4 xv = *(const float4*)(xr + h0);
        #pragma unroll
        for (int j = 0; j < 4; ++j) {
            float xs = (&xv.x)[j];
            const float4* wr = (const float4*)(Wg + (size_t)(h0 + j) * NEXP);
            float4 wa = wr[0], wb = wr[1];
            acc[0] = fmaf(xs, wa.x, acc[0]);
            acc[1] = fmaf(xs, wa.y, acc[1]);
            acc[2] = fmaf(xs, wa.z, acc[2]);
            acc[3] = fmaf(xs, wa.w, acc[3]);
            acc[4] = fmaf(xs, wb.x, acc[4]);
            acc[5] = fmaf(xs, wb.y, acc[5]);
            acc[6] = fmaf(xs, wb.z, acc[6]);
            acc[7] = fmaf(xs, wb.w, acc[7]);
        }
    }
    #pragma unroll
    for (int off = 32; off > 0; off >>= 1) {
        #pragma unroll
        for (int e = 0; e < 8; ++e) acc[e] += __shfl_down(acc[e], off, 64);
    }
    if (l == 0) {
        float lg[8];
        #pragma unroll
        for (int e = 0; e < 8; ++e) {
            lg[e] = acc[e] + bg[e];
            logits[(size_t)t * NEXP + e] = lg[e];
        }
        float m = lg[0];
        #pragma unroll
        for (int e = 1; e < 8; ++e) m = fmaxf(m, lg[e]);
        float p[8], s = 0.f;
        #pragma unroll
        for (int e = 0; e < 8; ++e) { p[e] = expf(lg[e] - m); s += p[e]; }
        float inv = 1.f / s;
        #pragma unroll
        for (int e = 0; e < 8; ++e) p[e] *= inv;
        int i0 = 0;
        #pragma unroll
        for (int e = 1; e < 8; ++e) if (p[e] > p[i0]) i0 = e;
        int i1 = (i0 == 0) ? 1 : 0;
        #pragma unroll
        for (int e = 0; e < 8; ++e) if (e != i0 && p[e] > p[i1]) i1 = e;
        float ed = expf(p[i1] - p[i0]);          // <= 1
        float w0 = 1.f / (1.f + ed);
        float w1 = ed / (1.f + ed);
        e0a[t] = i0; e1a[t] = i1; w0a[t] = w0; w1a[t] = w1;
        atomicAdd(&counts[i0], 1);
        atomicAdd(&counts[i1], 1);
    }
}

// ---------------- offsets: pad each expert segment to 128 rows ----------------
__global__ void offsets_kernel(const int* __restrict__ counts, int* __restrict__ off) {
    if (threadIdx.x == 0) {
        int o = 0;
        for (int e = 0; e < 8; ++e) { off[e] = o; o += (counts[e] + 127) & ~127; }
        off[8] = o;
    }
}

// ---------------- assign rows ----------------
__global__ __launch_bounds__(256) void assign_kernel(
    const int* __restrict__ e0a, const int* __restrict__ e1a,
    const int* __restrict__ off, int* __restrict__ fill,
    int* __restrict__ row0, int* __restrict__ row1, int* __restrict__ row_token)
{
    int t = blockIdx.x * 256 + threadIdx.x;
    if (t >= T_TOKENS) return;
    int e0 = e0a[t];
    int r0 = off[e0] + atomicAdd(&fill[e0], 1);
    row0[t] = r0; row_token[r0] = t;
    int e1 = e1a[t];
    int r1 = off[e1] + atomicAdd(&fill[e1], 1);
    row1[t] = r1; row_token[r1] = t;
}

// ---------------- gather x rows -> bf16 X_perm (zeros in padding rows) ----------------
__global__ __launch_bounds__(256) void gather_kernel(
    const float* __restrict__ x, const int* __restrict__ row_token, ushort* __restrict__ Xp)
{
    int r = blockIdx.x;
    int tok = row_token[r];
    int c = threadIdx.x * 4;
    ushort4 o;
    if (tok >= 0 && tok < T_TOKENS) {
        float4 v = *(const float4*)(x + (size_t)tok * HD + c);
        o.x = f2b(v.x); o.y = f2b(v.y); o.z = f2b(v.z); o.w = f2b(v.w);
    } else {
        o.x = 0; o.y = 0; o.z = 0; o.w = 0;
    }
    *(ushort4*)(Xp + (size_t)r * HD + c) = o;
}

// ---------------- fp32 [R][C] -> bf16 [C][R] transpose+convert (per expert in z) ----------------
__global__ __launch_bounds__(256) void transpose_cvt_kernel(
    const float* __restrict__ in, ushort* __restrict__ out, int R, int C)
{
    __shared__ ushort tile[64][65];
    size_t esz = (size_t)R * C;
    const float* ein = in + (size_t)blockIdx.z * esz;
    ushort* eout = out + (size_t)blockIdx.z * esz;
    int c0 = blockIdx.x * 64, r0 = blockIdx.y * 64;
    int tr = threadIdx.x >> 4;            // 0..15
    int tc = (threadIdx.x & 15) * 4;      // 0..60
    #pragma unroll
    for (int i = 0; i < 4; ++i) {
        int r = tr + i * 16;
        float4 v = *(const float4*)(ein + (size_t)(r0 + r) * C + c0 + tc);
        tile[r][tc + 0] = f2b(v.x);
        tile[r][tc + 1] = f2b(v.y);
        tile[r][tc + 2] = f2b(v.z);
        tile[r][tc + 3] = f2b(v.w);
    }
    __syncthreads();
    int twc = threadIdx.x >> 3;           // 0..31 : output row (input col) within tile
    int twr = (threadIdx.x & 7) * 8;      // 0..56 : output col (input row) base
    #pragma unroll
    for (int i = 0; i < 2; ++i) {
        int cc = twc + i * 32;
        ushort8v v;
        #pragma unroll
        for (int j = 0; j < 8; ++j) v[j] = tile[twr + j][cc];
        *(ushort8v*)(eout + (size_t)(c0 + cc) * R + r0 + twr) = v;   // 16B store
    }
}

// ---------------- MFMA GEMM: r4 structure + ring-3 counted-vmcnt (T3/T4 minimum) ----------------
// C[rows x NTOT] = A[rows x K] * B^T[NTOT x K] + bias, 128x128 tile, BK=32,
// 4 waves (2x2 of 64x64). Identical staging/swizzle/frag-read/MFMA body to the
// proven r4 kernel; ONLY the per-K-step sync changes:
//   __syncthreads (vmcnt(0)+lgkmcnt(0) drain)  ->  vmcnt(4) + s_barrier
// Ring-3 LDS; stage(t+2) at step top. Race-free: buf[s%3] last read at step s,
// next written by stage(s+3) issued after barrier B_{s+1}; vmcnt(4) at end of s
// retires exactly stage(s+1) (FIFO), leaving stage(s+2) in flight.
template<int K, int NTOT, bool RELU>
__global__ __launch_bounds__(256) void gemm_kernel(
    const ushort* __restrict__ A, const ushort* __restrict__ Bt,
    const float* __restrict__ bias, ushort* __restrict__ Out,
    const int* __restrict__ off)
{
    constexpr int NT = NTOT / 128;
    constexpr int KT = K / 32;
    __shared__ __align__(16) ushort lds[3][2][128 * 32];   // 48 KB ring-3

    // bijective XCD swizzle (gridDim.x % 8 == 0); n-fastest within each chunk
    int nwg = gridDim.x;
    int bid = blockIdx.x;
    int wgid = (bid & 7) * (nwg >> 3) + (bid >> 3);
    int ntile = wgid % NT;
    int mtile = wgid / NT;
    int r0 = mtile * 128;
    int total = off[8];
    if (r0 >= total) return;
    int e = 0;
    #pragma unroll
    for (int q = 0; q < 7; ++q) if (r0 >= off[q + 1]) e = q + 1;

    int tid = threadIdx.x;
    int w = tid >> 6, lane = tid & 63;
    int wr = w >> 1, wc = w & 1;
    int lr = lane & 15, lk = lane >> 4;

    const ushort* Ab = A + (size_t)r0 * K;
    const ushort* Bb = Bt + ((size_t)e * NTOT + (size_t)ntile * 128) * K;

    auto stage = [&](int kt, int sl) {
        #pragma unroll
        for (int issue = 0; issue < 2; ++issue) {
            int row = issue * 64 + w * 16 + (lane >> 2);
            int chunk = (lane & 3) ^ ((lane >> 3) & 3);   // pre-swizzle source
            const ushort* ga = Ab + (size_t)kt * 32 + (size_t)row * K + chunk * 8;
            const ushort* gb = Bb + (size_t)kt * 32 + (size_t)row * K + chunk * 8;
            ushort* la = &lds[sl][0][(issue * 64 + w * 16) * 32];
            ushort* lb = &lds[sl][1][(issue * 64 + w * 16) * 32];
            __builtin_amdgcn_global_load_lds(
                (const __attribute__((address_space(1))) void*)ga,
                (__attribute__((address_space(3))) void*)la, 16, 0, 0);
            __builtin_amdgcn_global_load_lds(
                (const __attribute__((address_space(1))) void*)gb,
                (__attribute__((address_space(3))) void*)lb, 16, 0, 0);
        }
    };

    f32x4 acc[4][4];
    #pragma unroll
    for (int mi = 0; mi < 4; ++mi)
        #pragma unroll
        for (int ni = 0; ni < 4; ++ni) acc[mi][ni] = (f32x4){0.f, 0.f, 0.f, 0.f};

    // prologue: stage K-steps 0 and 1; wait for 0 only (counted), 1 stays in flight
    stage(0, 0);
    stage(1, 1);
    asm volatile("s_waitcnt vmcnt(4)" ::: "memory");
    __builtin_amdgcn_sched_barrier(0);
    __builtin_amdgcn_s_barrier();

    int cur = 0, nx2 = 2;
    int slot = lk ^ ((lr >> 1) & 3);                      // conflict-free read slot
    for (int kt = 0; kt < KT; ++kt) {
        if (kt + 2 < KT) stage(kt + 2, nx2);
        const ushort* As = &lds[cur][0][0];
        const ushort* Bs = &lds[cur][1][0];
        bf16x8 a[4], b[4];
        #pragma unroll
        for (int mi = 0; mi < 4; ++mi)
            a[mi] = *(const bf16x8*)(As + (wr * 64 + mi * 16 + lr) * 32 + slot * 8);
        #pragma unroll
        for (int ni = 0; ni < 4; ++ni)
            b[ni] = *(const bf16x8*)(Bs + (wc * 64 + ni * 16 + lr) * 32 + slot * 8);
        #pragma unroll
        for (int mi = 0; mi < 4; ++mi)
            #pragma unroll
            for (int ni = 0; ni < 4; ++ni)
                acc[mi][ni] = __builtin_amdgcn_mfma_f32_16x16x32_bf16(
                    a[mi], b[ni], acc[mi][ni], 0, 0, 0);
        if (kt + 1 < KT) {
            if (kt + 2 < KT) { asm volatile("s_waitcnt vmcnt(4)" ::: "memory"); }
            else             { asm volatile("s_waitcnt vmcnt(0)" ::: "memory"); }
            __builtin_amdgcn_sched_barrier(0);
            __builtin_amdgcn_s_barrier();
        }
        cur = (cur == 2) ? 0 : cur + 1;
        nx2 = (nx2 == 2) ? 0 : nx2 + 1;
    }

    // epilogue: bias (+ReLU) -> bf16 store. C/D map: col = lane&15, row = (lane>>4)*4 + j
    int c0 = ntile * 128 + wc * 64;
    int rbase = r0 + wr * 64;
    #pragma unroll
    for (int ni = 0; ni < 4; ++ni) {
        int n = c0 + ni * 16 + lr;
        float bv = bias[(size_t)e * NTOT + n];
        #pragma unroll
        for (int mi = 0; mi < 4; ++mi) {
            int m = rbase + mi * 16 + lk * 4;
            #pragma unroll
            for (int j = 0; j < 4; ++j) {
                float v = acc[mi][ni][j] + bv;
                if (RELU) v = fmaxf(v, 0.f);
                Out[(size_t)(m + j) * NTOT + n] = f2b(v);
            }
        }
    }
}

// ---------------- combine: out[t] = w0*Y[r0] + w1*Y[r1] ----------------
__global__ __launch_bounds__(256) void combine_kernel(
    const ushort* __restrict__ Y, const int* __restrict__ row0, const int* __restrict__ row1,
    const float* __restrict__ w0a, const float* __restrict__ w1a, float* __restrict__ out)
{
    int t = blockIdx.x;
    int c = threadIdx.x * 4;
    int r0 = row0[t], r1 = row1[t];
    float w0 = w0a[t], w1 = w1a[t];
    ushort4 ya = *(const ushort4*)(Y + (size_t)r0 * HD + c);
    ushort4 yb = *(const ushort4*)(Y + (size_t)r1 * HD + c);
    float4 o;
    o.x = w0 * b2f(ya.x) + w1 * b2f(yb.x);
    o.y = w0 * b2f(ya.y) + w1 * b2f(yb.y);
    o.z = w0 * b2f(ya.z) + w1 * b2f(yb.z);
    o.w = w0 * b2f(ya.w) + w1 * b2f(yb.w);
    *(float4*)(out + (size_t)t * HD + c) = o;
}

// ---------------- workspace layout ----------------
#define WSA(x) (((x) + 255) & ~(size_t)255)
static constexpr size_t OFF_COUNTS = 0;
static constexpr size_t OFF_FILL   = 64;
static constexpr size_t OFF_OFF    = 128;
static constexpr size_t OFF_E0     = 256;
static constexpr size_t OFF_E1     = OFF_E0 + (size_t)T_TOKENS * 4;
static constexpr size_t OFF_W0     = OFF_E1 + (size_t)T_TOKENS * 4;
static constexpr size_t OFF_W1A    = OFF_W0 + (size_t)T_TOKENS * 4;
static constexpr size_t OFF_R0     = OFF_W1A + (size_t)T_TOKENS * 4;
static constexpr size_t OFF_R1     = OFF_R0 + (size_t)T_TOKENS * 4;
static constexpr size_t OFF_RT     = OFF_R1 + (size_t)T_TOKENS * 4;
static constexpr size_t OFF_XP     = WSA(OFF_RT + (size_t)NR_MAX * 4);
static constexpr size_t OFF_W1T    = OFF_XP  + (size_t)NR_MAX * HD * 2;
static constexpr size_t OFF_W2T    = OFF_W1T + (size_t)NEXP * FF * HD * 2;
static constexpr size_t OFF_H1     = OFF_W2T + (size_t)NEXP * HD * FF * 2;
static constexpr size_t OFF_Y      = OFF_H1  + (size_t)NR_MAX * FF * 2;
static constexpr size_t WS_NEEDED  = OFF_Y   + (size_t)NR_MAX * HD * 2;

extern "C" void kernel_launch(void* const* d_in, const int* in_sizes, int n_in,
                              void* d_out, int out_size, void* d_ws, size_t ws_size,
                              hipStream_t stream) {
    (void)in_sizes; (void)n_in; (void)out_size;
    const float* x  = (const float*)d_in[0];
    const float* Wg = (const float*)d_in[1];
    const float* bg = (const float*)d_in[2];
    const float* W1 = (const float*)d_in[3];
    const float* b1 = (const float*)d_in[4];
    const float* W2 = (const float*)d_in[5];
    const float* b2 = (const float*)d_in[6];
    float* out    = (float*)d_out;
    float* logits = out + (size_t)T_TOKENS * HD;

    if (ws_size < WS_NEEDED) return;  // need ~349 MB scratch

    char* ws = (char*)d_ws;
    int*    counts = (int*)(ws + OFF_COUNTS);
    int*    fill   = (int*)(ws + OFF_FILL);
    int*    offp   = (int*)(ws + OFF_OFF);
    int*    e0a    = (int*)(ws + OFF_E0);
    int*    e1a    = (int*)(ws + OFF_E1);
    float*  w0a    = (float*)(ws + OFF_W0);
    float*  w1a    = (float*)(ws + OFF_W1A);
    int*    row0   = (int*)(ws + OFF_R0);
    int*    row1   = (int*)(ws + OFF_R1);
    int*    rowtok = (int*)(ws + OFF_RT);
    ushort* Xp     = (ushort*)(ws + OFF_XP);
    ushort* W1T    = (ushort*)(ws + OFF_W1T);
    ushort* W2T    = (ushort*)(ws + OFF_W2T);
    ushort* H1     = (ushort*)(ws + OFF_H1);
    ushort* Y      = (ushort*)(ws + OFF_Y);

    hipMemsetAsync(ws, 0, 256, stream);                         // counts/fill/off
    hipMemsetAsync(rowtok, 0xFF, (size_t)NR_MAX * 4, stream);   // row_token = -1

    gate_kernel<<<T_TOKENS / 4, 256, 0, stream>>>(x, Wg, bg, logits, counts, e0a, e1a, w0a, w1a);
    offsets_kernel<<<1, 64, 0, stream>>>(counts, offp);
    assign_kernel<<<T_TOKENS / 256, 256, 0, stream>>>(e0a, e1a, offp, fill, row0, row1, rowtok);
    gather_kernel<<<NR_MAX, 256, 0, stream>>>(x, rowtok, Xp);
    transpose_cvt_kernel<<<dim3(FF / 64, HD / 64, NEXP), 256, 0, stream>>>(W1, W1T, HD, FF);
    transpose_cvt_kernel<<<dim3(HD / 64, FF / 64, NEXP), 256, 0, stream>>>(W2, W2T, FF, HD);
    gemm_kernel<HD, FF, true>
        <<<(FF / 128) * (NR_MAX / 128), 256, 0, stream>>>(Xp, W1T, b1, H1, offp);
    gemm_kernel<FF, HD, false>
        <<<(HD / 128) * (NR_MAX / 128), 256, 0, stream>>>(H1, W2T, b2, Y, offp);
    combine_kernel<<<T_TOKENS, 256, 0, stream>>>(Y, row0, row1, w0a, w1a, out);
}

// Round 9
// 772.529 us; speedup vs baseline: 1.1563x; 1.0288x over previous
//
#include <hip/hip_runtime.h>
#include <hip/hip_bf16.h>

// ---------------- problem constants ----------------
#define T_TOKENS 8192
#define HD 1024
#define FF 4096
#define NEXP 8
#define NR_MAX 17408   // 16384 picks + 8 experts * 127 max pad, rounded to 128

typedef __attribute__((ext_vector_type(8))) short bf16x8;
typedef __attribute__((ext_vector_type(4))) float f32x4;
typedef unsigned short ushort8v __attribute__((ext_vector_type(8)));

static __device__ __forceinline__ float b2f(ushort u) {
    union { unsigned u; float f; } c; c.u = ((unsigned)u) << 16; return c.f;
}
static __device__ __forceinline__ ushort f2b(float f) {
    union { float f; unsigned u; } c; c.f = f;
    unsigned r = c.u + 0x7fffu + ((c.u >> 16) & 1u);   // RNE
    return (ushort)(r >> 16);
}

// ---------------- gate: logits, softmax, top-2, counts ----------------
__global__ __launch_bounds__(256) void gate_kernel(
    const float* __restrict__ x, const float* __restrict__ Wg, const float* __restrict__ bg,
    float* __restrict__ logits, int* __restrict__ counts,
    int* __restrict__ e0a, int* __restrict__ e1a,
    float* __restrict__ w0a, float* __restrict__ w1a)
{
    int t = blockIdx.x * 4 + (threadIdx.x >> 6);
    int l = threadIdx.x & 63;
    const float* xr = x + (size_t)t * HD;
    float acc[8] = {0,0,0,0,0,0,0,0};
    #pragma unroll
    for (int i = 0; i < 4; ++i) {
        int h0 = i * 256 + l * 4;
        float4 xv = *(const float4*)(xr + h0);
        #pragma unroll
        for (int j = 0; j < 4; ++j) {
            float xs = (&xv.x)[j];
            const float4* wr = (const float4*)(Wg + (size_t)(h0 + j) * NEXP);
            float4 wa = wr[0], wb = wr[1];
            acc[0] = fmaf(xs, wa.x, acc[0]);
            acc[1] = fmaf(xs, wa.y, acc[1]);
            acc[2] = fmaf(xs, wa.z, acc[2]);
            acc[3] = fmaf(xs, wa.w, acc[3]);
            acc[4] = fmaf(xs, wb.x, acc[4]);
            acc[5] = fmaf(xs, wb.y, acc[5]);
            acc[6] = fmaf(xs, wb.z, acc[6]);
            acc[7] = fmaf(xs, wb.w, acc[7]);
        }
    }
    #pragma unroll
    for (int off = 32; off > 0; off >>= 1) {
        #pragma unroll
        for (int e = 0; e < 8; ++e) acc[e] += __shfl_down(acc[e], off, 64);
    }
    if (l == 0) {
        float lg[8];
        #pragma unroll
        for (int e = 0; e < 8; ++e) {
            lg[e] = acc[e] + bg[e];
            logits[(size_t)t * NEXP + e] = lg[e];
        }
        float m = lg[0];
        #pragma unroll
        for (int e = 1; e < 8; ++e) m = fmaxf(m, lg[e]);
        float p[8], s = 0.f;
        #pragma unroll
        for (int e = 0; e < 8; ++e) { p[e] = expf(lg[e] - m); s += p[e]; }
        float inv = 1.f / s;
        #pragma unroll
        for (int e = 0; e < 8; ++e) p[e] *= inv;
        int i0 = 0;
        #pragma unroll
        for (int e = 1; e < 8; ++e) if (p[e] > p[i0]) i0 = e;
        int i1 = (i0 == 0) ? 1 : 0;
        #pragma unroll
        for (int e = 0; e < 8; ++e) if (e != i0 && p[e] > p[i1]) i1 = e;
        float ed = expf(p[i1] - p[i0]);          // <= 1
        float w0 = 1.f / (1.f + ed);
        float w1 = ed / (1.f + ed);
        e0a[t] = i0; e1a[t] = i1; w0a[t] = w0; w1a[t] = w1;
        atomicAdd(&counts[i0], 1);
        atomicAdd(&counts[i1], 1);
    }
}

// ---------------- assign rows (offsets folded in; block 0 publishes off[]) ----------------
__global__ __launch_bounds__(256) void assign_kernel(
    const int* __restrict__ e0a, const int* __restrict__ e1a,
    const int* __restrict__ counts, int* __restrict__ fill, int* __restrict__ offg,
    int* __restrict__ row0, int* __restrict__ row1, int* __restrict__ row_token)
{
    __shared__ int off[9];
    if (threadIdx.x == 0) {
        int o = 0;
        #pragma unroll
        for (int e = 0; e < 8; ++e) { off[e] = o; o += (counts[e] + 127) & ~127; }
        off[8] = o;
        if (blockIdx.x == 0) {
            #pragma unroll
            for (int i = 0; i < 9; ++i) offg[i] = off[i];
        }
    }
    __syncthreads();
    int t = blockIdx.x * 256 + threadIdx.x;
    if (t >= T_TOKENS) return;
    int e0 = e0a[t];
    int r0 = off[e0] + atomicAdd(&fill[e0], 1);
    row0[t] = r0; row_token[r0] = t;
    int e1 = e1a[t];
    int r1 = off[e1] + atomicAdd(&fill[e1], 1);
    row1[t] = r1; row_token[r1] = t;
}

// ---------------- gather x rows -> bf16 X_perm (zeros in padding rows) ----------------
// 2 rows per block; 32B read / 16B store per lane.
__global__ __launch_bounds__(256) void gather_kernel(
    const float* __restrict__ x, const int* __restrict__ row_token, ushort* __restrict__ Xp)
{
    int r = blockIdx.x * 2 + (threadIdx.x >> 7);
    int c = (threadIdx.x & 127) * 8;
    int tok = row_token[r];
    ushort8v o;
    if (tok >= 0 && tok < T_TOKENS) {
        const float* src = x + (size_t)tok * HD + c;
        float4 v1 = *(const float4*)(src);
        float4 v2 = *(const float4*)(src + 4);
        o[0] = f2b(v1.x); o[1] = f2b(v1.y); o[2] = f2b(v1.z); o[3] = f2b(v1.w);
        o[4] = f2b(v2.x); o[5] = f2b(v2.y); o[6] = f2b(v2.z); o[7] = f2b(v2.w);
    } else {
        o = (ushort8v){0,0,0,0,0,0,0,0};
    }
    *(ushort8v*)(Xp + (size_t)r * HD + c) = o;
}

// ---------------- fused fp32 [R][C] -> bf16 [C][R] transpose+convert, W1 and W2 ----------------
// fp32 LDS [64][65]; 16B coalesced global loads and stores.
// W1: 8192 blocks (1024 tiles/expert: 16 row-tiles x 64 col-tiles).
// W2: 8192 blocks (1024 tiles/expert: 64 row-tiles x 16 col-tiles).
__global__ __launch_bounds__(256) void transpose_cvt_all(
    const float* __restrict__ W1, const float* __restrict__ W2,
    ushort* __restrict__ W1T, ushort* __restrict__ W2T)
{
    __shared__ float tile[64][65];
    int b = blockIdx.x;
    const float* in; ushort* out; int R, C, tid2, clog;
    if (b < 8192) {              // W1: [HD][FF] per expert -> [FF][HD]
        int e = b >> 10; tid2 = b & 1023;
        in = W1 + (size_t)e * HD * FF; out = W1T + (size_t)e * HD * FF;
        R = HD; C = FF; clog = 6;                 // 16 x 64 tiles
    } else {                     // W2: [FF][HD] per expert -> [HD][FF]
        int bb = b - 8192; int e = bb >> 10; tid2 = bb & 1023;
        in = W2 + (size_t)e * FF * HD; out = W2T + (size_t)e * FF * HD;
        R = FF; C = HD; clog = 4;                 // 64 x 16 tiles
    }
    int rt = tid2 >> clog, ct = tid2 & ((1 << clog) - 1);
    int r0 = rt * 64, c0 = ct * 64;

    int tr = threadIdx.x >> 4;            // 0..15
    int tc = (threadIdx.x & 15) * 4;      // 0..60
    #pragma unroll
    for (int i = 0; i < 4; ++i) {
        int r = tr + i * 16;
        float4 v = *(const float4*)(in + (size_t)(r0 + r) * C + c0 + tc);
        tile[r][tc + 0] = v.x;
        tile[r][tc + 1] = v.y;
        tile[r][tc + 2] = v.z;
        tile[r][tc + 3] = v.w;
    }
    __syncthreads();
    int cc = threadIdx.x >> 3;            // 0..31
    int rr = (threadIdx.x & 7) * 8;       // 0..56
    #pragma unroll
    for (int i = 0; i < 2; ++i) {
        int c = cc + i * 32;
        ushort8v o;
        #pragma unroll
        for (int j = 0; j < 8; ++j) o[j] = f2b(tile[rr + j][c]);
        *(ushort8v*)(out + (size_t)(c0 + c) * R + r0 + rr) = o;   // 16B store
    }
}

// ---------------- MFMA GEMM (r4-proven structure; MFAST: m-fastest chunked swizzle) ----------------
// C[rows x NTOT] = A[rows x K] * B^T[NTOT x K] + bias, 128x128 tile, BK=32,
// 4 waves (2x2 of 64x64), compiler-scheduled 2-barrier dbuf loop,
// global_load_lds width 16 with pre-swizzled source (0 bank conflicts).
// MFAST=true: within each XCD chunk iterate m fastest (B-panel L2-resident);
// MFAST=false: n fastest (A-tile L2-resident).
template<int K, int NTOT, bool RELU, bool MFAST>
__global__ __launch_bounds__(256, 4) void gemm_kernel(
    const ushort* __restrict__ A, const ushort* __restrict__ Bt,
    const float* __restrict__ bias, ushort* __restrict__ Out,
    const int* __restrict__ off)
{
    constexpr int NT = NTOT / 128;
    __shared__ __align__(16) ushort lds[2][2][128 * 32];

    int nwg = gridDim.x;
    int chunkc = nwg >> 3;
    int cid = blockIdx.x & 7, q = blockIdx.x >> 3;
    int mtile, ntile;
    if constexpr (MFAST) {
        int mloc = chunkc / NT;                  // m-tiles per XCD chunk
        mtile = cid * mloc + q % mloc;
        ntile = q / mloc;
    } else {
        int wgid = cid * chunkc + q;
        ntile = wgid % NT;
        mtile = wgid / NT;
    }
    int r0 = mtile * 128;
    int total = off[8];
    if (r0 >= total) return;
    int e = 0;
    #pragma unroll
    for (int qq = 0; qq < 7; ++qq) if (r0 >= off[qq + 1]) e = qq + 1;

    int tid = threadIdx.x;
    int w = tid >> 6, lane = tid & 63;
    int wr = w >> 1, wc = w & 1;
    int lr = lane & 15, lk = lane >> 4;

    const ushort* Ab = A + (size_t)r0 * K;
    const ushort* Bb = Bt + ((size_t)e * NTOT + (size_t)ntile * 128) * K;

    auto stage = [&](const ushort* gbase, ushort* ldsbase) {
        #pragma unroll
        for (int issue = 0; issue < 2; ++issue) {
            int row = issue * 64 + w * 16 + (lane >> 2);
            int chunk = (lane & 3) ^ ((lane >> 3) & 3);   // pre-swizzle source
            const ushort* g = gbase + (size_t)row * K + chunk * 8;
            ushort* lp = ldsbase + (issue * 64 + w * 16) * 32;
            __builtin_amdgcn_global_load_lds(
                (const __attribute__((address_space(1))) void*)g,
                (__attribute__((address_space(3))) void*)lp, 16, 0, 0);
        }
    };

    stage(Ab, &lds[0][0][0]);
    stage(Bb, &lds[0][1][0]);

    f32x4 acc[4][4];
    #pragma unroll
    for (int mi = 0; mi < 4; ++mi)
        #pragma unroll
        for (int ni = 0; ni < 4; ++ni) acc[mi][ni] = (f32x4){0.f, 0.f, 0.f, 0.f};

    __syncthreads();

    constexpr int KT = K / 32;
    int cur = 0;
    int slot = lk ^ ((lr >> 1) & 3);                      // swizzled read slot
    for (int kt = 0; kt < KT; ++kt) {
        if (kt + 1 < KT) {
            stage(Ab + (kt + 1) * 32, &lds[cur ^ 1][0][0]);
            stage(Bb + (kt + 1) * 32, &lds[cur ^ 1][1][0]);
        }
        const ushort* As = &lds[cur][0][0];
        const ushort* Bs = &lds[cur][1][0];
        bf16x8 a[4], b[4];
        #pragma unroll
        for (int mi = 0; mi < 4; ++mi)
            a[mi] = *(const bf16x8*)(As + (wr * 64 + mi * 16 + lr) * 32 + slot * 8);
        #pragma unroll
        for (int ni = 0; ni < 4; ++ni)
            b[ni] = *(const bf16x8*)(Bs + (wc * 64 + ni * 16 + lr) * 32 + slot * 8);
        #pragma unroll
        for (int mi = 0; mi < 4; ++mi)
            #pragma unroll
            for (int ni = 0; ni < 4; ++ni)
                acc[mi][ni] = __builtin_amdgcn_mfma_f32_16x16x32_bf16(
                    a[mi], b[ni], acc[mi][ni], 0, 0, 0);
        __syncthreads();
        cur ^= 1;
    }

    // epilogue: bias (+ReLU) -> bf16 store. C/D map: col = lane&15, row = (lane>>4)*4 + j
    int c0 = ntile * 128 + wc * 64;
    int rbase = r0 + wr * 64;
    #pragma unroll
    for (int ni = 0; ni < 4; ++ni) {
        int n = c0 + ni * 16 + lr;
        float bv = bias[(size_t)e * NTOT + n];
        #pragma unroll
        for (int mi = 0; mi < 4; ++mi) {
            int m = rbase + mi * 16 + lk * 4;
            #pragma unroll
            for (int j = 0; j < 4; ++j) {
                float v = acc[mi][ni][j] + bv;
                if (RELU) v = fmaxf(v, 0.f);
                Out[(size_t)(m + j) * NTOT + n] = f2b(v);
            }
        }
    }
}

// ---------------- combine: out[t] = w0*Y[r0] + w1*Y[r1] ----------------
__global__ __launch_bounds__(256) void combine_kernel(
    const ushort* __restrict__ Y, const int* __restrict__ row0, const int* __restrict__ row1,
    const float* __restrict__ w0a, const float* __restrict__ w1a, float* __restrict__ out)
{
    int t = blockIdx.x;
    int c = threadIdx.x * 4;
    int r0 = row0[t], r1 = row1[t];
    float w0 = w0a[t], w1 = w1a[t];
    ushort4 ya = *(const ushort4*)(Y + (size_t)r0 * HD + c);
    ushort4 yb = *(const ushort4*)(Y + (size_t)r1 * HD + c);
    float4 o;
    o.x = w0 * b2f(ya.x) + w1 * b2f(yb.x);
    o.y = w0 * b2f(ya.y) + w1 * b2f(yb.y);
    o.z = w0 * b2f(ya.z) + w1 * b2f(yb.z);
    o.w = w0 * b2f(ya.w) + w1 * b2f(yb.w);
    *(float4*)(out + (size_t)t * HD + c) = o;
}

// ---------------- workspace layout ----------------
#define WSA(x) (((x) + 255) & ~(size_t)255)
static constexpr size_t OFF_COUNTS = 0;
static constexpr size_t OFF_FILL   = 64;
static constexpr size_t OFF_OFF    = 128;
static constexpr size_t OFF_E0     = 256;
static constexpr size_t OFF_E1     = OFF_E0 + (size_t)T_TOKENS * 4;
static constexpr size_t OFF_W0     = OFF_E1 + (size_t)T_TOKENS * 4;
static constexpr size_t OFF_W1A    = OFF_W0 + (size_t)T_TOKENS * 4;
static constexpr size_t OFF_R0     = OFF_W1A + (size_t)T_TOKENS * 4;
static constexpr size_t OFF_R1     = OFF_R0 + (size_t)T_TOKENS * 4;
static constexpr size_t OFF_RT     = OFF_R1 + (size_t)T_TOKENS * 4;
static constexpr size_t OFF_XP     = WSA(OFF_RT + (size_t)NR_MAX * 4);
static constexpr size_t OFF_W1T    = OFF_XP  + (size_t)NR_MAX * HD * 2;
static constexpr size_t OFF_W2T    = OFF_W1T + (size_t)NEXP * FF * HD * 2;
static constexpr size_t OFF_H1     = OFF_W2T + (size_t)NEXP * HD * FF * 2;
static constexpr size_t OFF_Y      = OFF_H1  + (size_t)NR_MAX * FF * 2;
static constexpr size_t WS_NEEDED  = OFF_Y   + (size_t)NR_MAX * HD * 2;

extern "C" void kernel_launch(void* const* d_in, const int* in_sizes, int n_in,
                              void* d_out, int out_size, void* d_ws, size_t ws_size,
                              hipStream_t stream) {
    (void)in_sizes; (void)n_in; (void)out_size;
    const float* x  = (const float*)d_in[0];
    const float* Wg = (const float*)d_in[1];
    const float* bg = (const float*)d_in[2];
    const float* W1 = (const float*)d_in[3];
    const float* b1 = (const float*)d_in[4];
    const float* W2 = (const float*)d_in[5];
    const float* b2 = (const float*)d_in[6];
    float* out    = (float*)d_out;
    float* logits = out + (size_t)T_TOKENS * HD;

    if (ws_size < WS_NEEDED) return;  // need ~349 MB scratch

    char* ws = (char*)d_ws;
    int*    counts = (int*)(ws + OFF_COUNTS);
    int*    fill   = (int*)(ws + OFF_FILL);
    int*    offp   = (int*)(ws + OFF_OFF);
    int*    e0a    = (int*)(ws + OFF_E0);
    int*    e1a    = (int*)(ws + OFF_E1);
    float*  w0a    = (float*)(ws + OFF_W0);
    float*  w1a    = (float*)(ws + OFF_W1A);
    int*    row0   = (int*)(ws + OFF_R0);
    int*    row1   = (int*)(ws + OFF_R1);
    int*    rowtok = (int*)(ws + OFF_RT);
    ushort* Xp     = (ushort*)(ws + OFF_XP);
    ushort* W1T    = (ushort*)(ws + OFF_W1T);
    ushort* W2T    = (ushort*)(ws + OFF_W2T);
    ushort* H1     = (ushort*)(ws + OFF_H1);
    ushort* Y      = (ushort*)(ws + OFF_Y);

    hipMemsetAsync(ws, 0, 256, stream);                         // counts/fill/off
    hipMemsetAsync(rowtok, 0xFF, (size_t)NR_MAX * 4, stream);   // row_token = -1

    gate_kernel<<<T_TOKENS / 4, 256, 0, stream>>>(x, Wg, bg, logits, counts, e0a, e1a, w0a, w1a);
    assign_kernel<<<T_TOKENS / 256, 256, 0, stream>>>(e0a, e1a, counts, fill, offp, row0, row1, rowtok);
    gather_kernel<<<NR_MAX / 2, 256, 0, stream>>>(x, rowtok, Xp);
    transpose_cvt_all<<<8192 + 8192, 256, 0, stream>>>(W1, W2, W1T, W2T);
    gemm_kernel<HD, FF, true, true>
        <<<(FF / 128) * (NR_MAX / 128), 256, 0, stream>>>(Xp, W1T, b1, H1, offp);
    gemm_kernel<FF, HD, false, false>
        <<<(HD / 128) * (NR_MAX / 128), 256, 0, stream>>>(H1, W2T, b2, Y, offp);
    combine_kernel<<<T_TOKENS, 256, 0, stream>>>(Y, row0, row1, w0a, w1a, out);
}